// Round 1
// baseline (63.447 us; speedup 1.0000x reference)
//
#include <hip/hip_runtime.h>
#include <math.h>

#define H 2048
#define Wd 256
#define DEPTH 1024
#define V 128

// ws float layout:
//  [0..2]   : a_push, a_pop, a_noop (softmaxed ctrl)
//  [4..259] : stack_in[256]
//  [320..2623] : rnn_in[2304]  (2048 emb || 256 stack_top)
//  [4096..20479] : g[16384]  (fwd 8192, bwd 8192)
#define WS_A      0
#define WS_SIN    4
#define WS_RNNIN  320
#define WS_G      4096

__device__ __forceinline__ float wave_reduce(float v) {
    #pragma unroll
    for (int off = 32; off; off >>= 1) v += __shfl_xor(v, off, 64);
    return v;
}

__device__ __forceinline__ float sigm(float x) { return 1.f / (1.f + expf(-x)); }

// Kernel 1: ctrl (3x4096 matvec + softmax) and stack_in (256x4096 matvec + tanh)
__global__ void k1_ctrl_stackin(const float* __restrict__ hidden,
                                const float* __restrict__ W_ctrl, const float* __restrict__ b_ctrl,
                                const float* __restrict__ W_sin, const float* __restrict__ b_sin,
                                float* __restrict__ ws) {
    const int b = blockIdx.x;
    const float4* hv = (const float4*)hidden;   // 1024 float4 = h2s (concat of hidden[0],hidden[1])
    if (b == 0) {
        __shared__ float dots[3];
        const int wave = threadIdx.x >> 6;
        const int lane = threadIdx.x & 63;
        if (wave < 3) {
            const float4* Wr = (const float4*)(W_ctrl + wave * (2 * H));
            float acc = 0.f;
            for (int k = lane; k < 1024; k += 64) {
                float4 w4 = Wr[k], h4 = hv[k];
                acc += w4.x * h4.x + w4.y * h4.y + w4.z * h4.z + w4.w * h4.w;
            }
            acc = wave_reduce(acc);
            if (lane == 0) dots[wave] = acc + b_ctrl[wave];
        }
        __syncthreads();
        if (threadIdx.x == 0) {
            float m = fmaxf(dots[0], fmaxf(dots[1], dots[2]));
            float e0 = expf(dots[0] - m), e1 = expf(dots[1] - m), e2 = expf(dots[2] - m);
            float s = e0 + e1 + e2;
            ws[WS_A + 0] = e0 / s;  // a_push
            ws[WS_A + 1] = e1 / s;  // a_pop
            ws[WS_A + 2] = e2 / s;  // a_noop
        }
    } else {
        const int r = b - 1;  // 0..255
        const float4* Wr = (const float4*)(W_sin + (size_t)r * (2 * H));
        float acc = 0.f;
        for (int k = threadIdx.x; k < 1024; k += 256) {
            float4 w4 = Wr[k], h4 = hv[k];
            acc += w4.x * h4.x + w4.y * h4.y + w4.z * h4.z + w4.w * h4.w;
        }
        __shared__ float red[4];
        acc = wave_reduce(acc);
        const int wave = threadIdx.x >> 6, lane = threadIdx.x & 63;
        if (lane == 0) red[wave] = acc;
        __syncthreads();
        if (threadIdx.x == 0) {
            float s = red[0] + red[1] + red[2] + red[3] + b_sin[r];
            ws[WS_SIN + r] = tanhf(s);
        }
    }
}

// Kernel 2: stack update (writes new_stack to d_out) + build rnn_in in ws
__global__ void k2_stack(const float* __restrict__ stack,
                         const float* __restrict__ emb, const int* __restrict__ inp,
                         const float* __restrict__ ws_in,
                         float* __restrict__ new_stack, float* __restrict__ rnn_in) {
    const int b = blockIdx.x;
    if (b < DEPTH) {
        const int d = b;
        const int w = threadIdx.x;  // 256 threads
        const float a_push = ws_in[WS_A + 0];
        const float a_pop  = ws_in[WS_A + 1];
        const float a_noop = ws_in[WS_A + 2];
        const float cur  = stack[d * Wd + w];
        const float up   = (d == 0) ? ws_in[WS_SIN + w] : stack[(d - 1) * Wd + w];
        const float down = (d == DEPTH - 1) ? 0.f : stack[(d + 1) * Wd + w];
        const float nv = a_noop * cur + a_push * up + a_pop * down;
        new_stack[d * Wd + w] = nv;
        if (d == 0) rnn_in[H + w] = nv;   // stack_top
    } else {
        const int j = (b - DEPTH) * 256 + threadIdx.x;  // 0..2047
        rnn_in[j] = emb[(size_t)inp[0] * H + j];
    }
}

// Kernel 3: LSTM gate matvecs, both directions. One wave per output row.
__global__ void __launch_bounds__(256) k3_gates(
        const float* __restrict__ rnn_in, const float* __restrict__ hidden,
        const float* __restrict__ w_ih_f, const float* __restrict__ w_hh_f,
        const float* __restrict__ b_ih_f, const float* __restrict__ b_hh_f,
        const float* __restrict__ w_ih_b, const float* __restrict__ w_hh_b,
        const float* __restrict__ b_ih_b, const float* __restrict__ b_hh_b,
        float* __restrict__ g) {
    const int r = (blockIdx.x * blockDim.x + threadIdx.x) >> 6;  // 0..16383
    const int lane = threadIdx.x & 63;
    const float* wih; const float* whh; const float* bih; const float* bhh;
    const float* h; int row;
    if (r < 4 * H) { wih = w_ih_f; whh = w_hh_f; bih = b_ih_f; bhh = b_hh_f; h = hidden;      row = r; }
    else           { wih = w_ih_b; whh = w_hh_b; bih = b_ih_b; bhh = b_hh_b; h = hidden + H; row = r - 4 * H; }

    const float4* wi = (const float4*)(wih + (size_t)row * (H + Wd));
    const float4* xi = (const float4*)rnn_in;
    float acc = 0.f;
    #pragma unroll
    for (int k = 0; k < 9; ++k) {   // 576 float4 = 2304 floats
        float4 w4 = wi[lane + 64 * k], x4 = xi[lane + 64 * k];
        acc += w4.x * x4.x + w4.y * x4.y + w4.z * x4.z + w4.w * x4.w;
    }
    const float4* wh = (const float4*)(whh + (size_t)row * H);
    const float4* hv = (const float4*)h;
    #pragma unroll
    for (int k = 0; k < 8; ++k) {   // 512 float4 = 2048 floats
        float4 w4 = wh[lane + 64 * k], h4 = hv[lane + 64 * k];
        acc += w4.x * h4.x + w4.y * h4.y + w4.z * h4.z + w4.w * h4.w;
    }
    acc = wave_reduce(acc);
    if (lane == 0) g[r] = acc + bih[row] + bhh[row];
}

// Kernel 4: gate nonlinearity -> new_hidden, new_cell (into d_out)
__global__ void k4_hc(const float* __restrict__ g, const float* __restrict__ cell,
                      float* __restrict__ out) {
    const int t = blockIdx.x * blockDim.x + threadIdx.x;  // 0..4095
    const int dir = t >> 11, j = t & (H - 1);
    const float* gd = g + dir * 4 * H;
    const float iv = gd[j], fv = gd[H + j], gv = gd[2 * H + j], ov = gd[3 * H + j];
    const float c_old = cell[dir * H + j];
    const float c2 = sigm(fv) * c_old + sigm(iv) * tanhf(gv);
    const float h2 = sigm(ov) * tanhf(c2);
    out[V + dir * H + j] = h2;             // new_hidden
    out[V + 2 * H + dir * H + j] = c2;     // new_cell
}

// Kernel 5: decoder logits = W_dec @ [h_f,h_b] + b_dec. One wave per row.
__global__ void k5_dec(const float* __restrict__ out_h, const float* __restrict__ W_dec,
                       const float* __restrict__ b_dec, float* __restrict__ logits) {
    const int r = (blockIdx.x * blockDim.x + threadIdx.x) >> 6;  // 0..127
    const int lane = threadIdx.x & 63;
    const float4* Wr = (const float4*)(W_dec + (size_t)r * (2 * H));
    const float4* hv = (const float4*)out_h;
    float acc = 0.f;
    #pragma unroll
    for (int k = 0; k < 16; ++k) {  // 1024 float4 = 4096 floats
        float4 w4 = Wr[lane + 64 * k], h4 = hv[lane + 64 * k];
        acc += w4.x * h4.x + w4.y * h4.y + w4.z * h4.z + w4.w * h4.w;
    }
    acc = wave_reduce(acc);
    if (lane == 0) logits[r] = acc + b_dec[r];
}

extern "C" void kernel_launch(void* const* d_in, const int* in_sizes, int n_in,
                              void* d_out, int out_size, void* d_ws, size_t ws_size,
                              hipStream_t stream) {
    const int*   inp    = (const int*)  d_in[0];
    const float* hidden = (const float*)d_in[1];
    const float* cell   = (const float*)d_in[2];
    const float* stack  = (const float*)d_in[3];
    const float* emb    = (const float*)d_in[4];
    const float* W_ctrl = (const float*)d_in[5];
    const float* b_ctrl = (const float*)d_in[6];
    const float* W_sin  = (const float*)d_in[7];
    const float* b_sin  = (const float*)d_in[8];
    const float* w_ih_f = (const float*)d_in[9];
    const float* w_hh_f = (const float*)d_in[10];
    const float* b_ih_f = (const float*)d_in[11];
    const float* b_hh_f = (const float*)d_in[12];
    const float* w_ih_b = (const float*)d_in[13];
    const float* w_hh_b = (const float*)d_in[14];
    const float* b_ih_b = (const float*)d_in[15];
    const float* b_hh_b = (const float*)d_in[16];
    const float* W_dec  = (const float*)d_in[17];
    const float* b_dec  = (const float*)d_in[18];

    float* out = (float*)d_out;
    float* ws  = (float*)d_ws;

    float* new_stack = out + V + 4 * H;      // offset 8320
    float* rnn_in    = ws + WS_RNNIN;
    float* g         = ws + WS_G;

    // K1: ctrl + stack_in
    k1_ctrl_stackin<<<257, 256, 0, stream>>>(hidden, W_ctrl, b_ctrl, W_sin, b_sin, ws);
    // K2: stack update + rnn_in assembly (1024 stack blocks + 8 emb blocks)
    k2_stack<<<DEPTH + 8, 256, 0, stream>>>(stack, emb, inp, ws, new_stack, rnn_in);
    // K3: gate matvecs, 16384 rows, 1 wave/row, 4 waves/block
    k3_gates<<<4096, 256, 0, stream>>>(rnn_in, hidden,
                                       w_ih_f, w_hh_f, b_ih_f, b_hh_f,
                                       w_ih_b, w_hh_b, b_ih_b, b_hh_b, g);
    // K4: h/c elementwise
    k4_hc<<<16, 256, 0, stream>>>(g, cell, out);
    // K5: decoder, 128 rows, 1 wave/row
    k5_dec<<<32, 256, 0, stream>>>(out + V, W_dec, b_dec, out);
}